// Round 1
// baseline (112.802 us; speedup 1.0000x reference)
//
#include <hip/hip_runtime.h>

// DTFormer: B=64, L=1024, S=8, D=128
// Structure (this round): 2 dispatches instead of 3.
//  K1 table_kernel : Phi[sn][c0][c1][128] for counts < 16 (unchanged, proven).
//  K2 fused_kernel : per-batch LDS histogram (built redundantly by the 4
//                    blocks that own the batch -> grid 256 = 1 block/CU)
//                    + direct table gather + 64MB coalesced output write.
//  Removes: cnt_src/cnt_dst global round-trip (1MB), one dispatch boundary.
// Timed floor is dominated by the harness's 268MB workspace poison fills
// (~43us each @ 77% HBM peak, see rocprof) — not addressable from here.

#define LSEQ 1024
#define NBATCH 64
#define DDIM 128
#define NKEYS 16384
#define CMAX 16

// ---------------- Kernel 1: build Phi table [8][16][16][128] ----------------
__global__ __launch_bounds__(128) void table_kernel(
    const float* __restrict__ agg_w1, const float* __restrict__ agg_b1,
    const float* __restrict__ agg_w2, const float* __restrict__ agg_b2,
    const float* __restrict__ enc_w1, const float* __restrict__ enc_b1,
    const float* __restrict__ enc_w2, const float* __restrict__ enc_b2,
    float* __restrict__ table)
{
    const int bx = blockIdx.x;          // [0, 8*16*16)
    const int sn = bx >> 8;
    const int c0 = (bx >> 4) & 15;
    const int c1 = bx & 15;
    const int d  = threadIdx.x;

    __shared__ float red0[DDIM], red1[DDIM], g[DDIM];

    // agg MLP layer 1+2 partials (y_e = b2[e] + 0.5*(psi_e(c0)+psi_e(c1)))
    const float w1d = agg_w1[sn * DDIM + d];
    const float b1d = agg_b1[d];
    const float h = fmaxf((float)c0 * w1d + b1d, 0.0f)
                  + fmaxf((float)c1 * w1d + b1d, 0.0f);
    red0[d] = h * agg_w2[d * 2 + 0];
    red1[d] = h * agg_w2[d * 2 + 1];
    __syncthreads();
    for (int s = 64; s > 0; s >>= 1) {
        if (d < s) { red0[d] += red0[d + s]; red1[d] += red1[d + s]; }
        __syncthreads();
    }
    const float y0 = agg_b2[0] + 0.5f * red0[0];
    const float y1 = agg_b2[1] + 0.5f * red1[0];
    __syncthreads();

    // encoder: g[k] = relu(y0*w1e+b1e) + relu(y1*w1e+b1e)
    const float w1e = enc_w1[d], b1e = enc_b1[d];
    g[d] = fmaxf(y0 * w1e + b1e, 0.0f) + fmaxf(y1 * w1e + b1e, 0.0f);
    __syncthreads();

    float acc = 2.0f * enc_b2[d];
    #pragma unroll 8
    for (int k = 0; k < DDIM; ++k)
        acc += g[k] * enc_w2[k * DDIM + d];
    table[bx * DDIM + d] = acc;
}

// -------- exact slow path (counts >= 16: statistically never hit) -----------
__device__ __noinline__ float4 slow_path(
    unsigned int c0, unsigned int c1, unsigned int sn, int q,
    const float* __restrict__ agg_w1, const float* __restrict__ agg_b1,
    const float* __restrict__ agg_w2, const float* __restrict__ agg_b2,
    const float* __restrict__ enc_w1, const float* __restrict__ enc_b1,
    const float* __restrict__ enc_w2, const float* __restrict__ enc_b2)
{
    float s0 = 0.0f, s1 = 0.0f;
    for (int dd = 0; dd < DDIM; ++dd) {
        const float w1d = agg_w1[sn * DDIM + dd];
        const float b1d = agg_b1[dd];
        const float h = fmaxf((float)c0 * w1d + b1d, 0.0f)
                      + fmaxf((float)c1 * w1d + b1d, 0.0f);
        s0 += h * agg_w2[dd * 2 + 0];
        s1 += h * agg_w2[dd * 2 + 1];
    }
    const float y0 = agg_b2[0] + 0.5f * s0;
    const float y1 = agg_b2[1] + 0.5f * s1;
    float o0 = 2.0f * enc_b2[q * 4 + 0];
    float o1 = 2.0f * enc_b2[q * 4 + 1];
    float o2 = 2.0f * enc_b2[q * 4 + 2];
    float o3 = 2.0f * enc_b2[q * 4 + 3];
    for (int k = 0; k < DDIM; ++k) {
        const float w1e = enc_w1[k], b1e = enc_b1[k];
        const float gk = fmaxf(y0 * w1e + b1e, 0.0f)
                       + fmaxf(y1 * w1e + b1e, 0.0f);
        o0 += gk * enc_w2[k * DDIM + q * 4 + 0];
        o1 += gk * enc_w2[k * DDIM + q * 4 + 1];
        o2 += gk * enc_w2[k * DDIM + q * 4 + 2];
        o3 += gk * enc_w2[k * DDIM + q * 4 + 3];
    }
    return make_float4(o0, o1, o2, o3);
}

// ---------- Kernel 2: fused per-batch histogram + gather + write ------------
// grid = NBATCH*4 = 256 blocks (1/CU), block = 1024 threads.
// Each of the 4 blocks of a batch rebuilds the full (id,snap) histogram in
// LDS (cheap, removes a kernel boundary + global cnt round-trip), then owns
// 512 of the batch's 2048 output rows (2 sides x 1024 l), 128 floats each.
__global__ __launch_bounds__(1024) void fused_kernel(
    const int* __restrict__ src_ids, const int* __restrict__ dst_ids,
    const int* __restrict__ src_sn,  const int* __restrict__ dst_sn,
    const float* __restrict__ table,
    const float* __restrict__ agg_w1, const float* __restrict__ agg_b1,
    const float* __restrict__ agg_w2, const float* __restrict__ agg_b2,
    const float* __restrict__ enc_w1, const float* __restrict__ enc_b1,
    const float* __restrict__ enc_w2, const float* __restrict__ enc_b2,
    float* __restrict__ out)
{
    __shared__ unsigned int hist[NKEYS];   // src count in lo16, dst count in hi16
    const int b = blockIdx.x >> 2;
    const int r = blockIdx.x & 3;
    const int t = threadIdx.x;

    #pragma unroll
    for (int i = 0; i < NKEYS / 1024; ++i) hist[i * 1024 + t] = 0u;
    __syncthreads();

    const int base = b * LSEQ;
    {
        const int sid = src_ids[base + t];
        const int ssn = src_sn[base + t];
        const int did = dst_ids[base + t];
        const int dsn = dst_sn[base + t];
        unsigned int skey = (unsigned int)(sid * 8 + ((ssn - 1) & 7));
        unsigned int dkey = (unsigned int)(did * 8 + ((dsn - 1) & 7));
        if (skey >= NKEYS) skey = NKEYS - 1;   // safety clamp (never hit: id<2000)
        if (dkey >= NKEYS) dkey = NKEYS - 1;
        atomicAdd(&hist[skey], 1u);
        atomicAdd(&hist[dkey], 65536u);
    }
    __syncthreads();

    // gather phase: 32 units of 32 lanes; unit handles one 128-float row.
    const int unit = t >> 5;
    const int q    = t & 31;

    #pragma unroll 1
    for (int i = 0; i < 16; ++i) {
        const int row  = r * 512 + i * 32 + unit;   // [0, 2048) within batch
        const int side = row >> 10;
        const int l    = row & 1023;

        const int id = side ? dst_ids[base + l] : src_ids[base + l];
        const int sn = side ? dst_sn[base + l]  : src_sn[base + l];

        unsigned int key = (unsigned int)(id * 8 + ((sn - 1) & 7));
        if (key >= NKEYS) key = NKEYS - 1;
        const unsigned int h = hist[key];
        unsigned int c0 = side ? (h >> 16)     : (h & 0xffffu);  // self
        unsigned int c1 = side ? (h & 0xffffu) : (h >> 16);      // cross
        if (id == 0) { c0 = 0u; c1 = 0u; }
        const unsigned int snn = (unsigned int)((sn - 1) & 7);

        float4 v;
        if (c0 < CMAX && c1 < CMAX) {
            const float4* srcp = (const float4*)(table
                + ((snn * 256u + c0 * 16u + c1) * DDIM));
            v = srcp[q];
        } else {
            v = slow_path(c0, c1, snn, q, agg_w1, agg_b1, agg_w2, agg_b2,
                          enc_w1, enc_b1, enc_w2, enc_b2);
        }
        ((float4*)out)[((size_t)side * (NBATCH * LSEQ) + base + l) * 32 + q] = v;
    }
}

extern "C" void kernel_launch(void* const* d_in, const int* in_sizes, int n_in,
                              void* d_out, int out_size, void* d_ws, size_t ws_size,
                              hipStream_t stream)
{
    const int* src_ids = (const int*)d_in[0];
    const int* dst_ids = (const int*)d_in[1];
    const int* src_sn  = (const int*)d_in[2];
    const int* dst_sn  = (const int*)d_in[3];
    // d_in[4] = num_snapshots (hardcoded 8)
    const float* agg_w1 = (const float*)d_in[5];
    const float* agg_b1 = (const float*)d_in[6];
    const float* agg_w2 = (const float*)d_in[7];
    const float* agg_b2 = (const float*)d_in[8];
    const float* enc_w1 = (const float*)d_in[9];
    const float* enc_b1 = (const float*)d_in[10];
    const float* enc_w2 = (const float*)d_in[11];
    const float* enc_b2 = (const float*)d_in[12];
    float* out = (float*)d_out;

    // ws layout: table[2048*128] f32 (cnt round-trip eliminated)
    float* table = (float*)d_ws;

    table_kernel<<<8 * CMAX * CMAX, 128, 0, stream>>>(
        agg_w1, agg_b1, agg_w2, agg_b2, enc_w1, enc_b1, enc_w2, enc_b2, table);
    fused_kernel<<<NBATCH * 4, 1024, 0, stream>>>(
        src_ids, dst_ids, src_sn, dst_sn, table,
        agg_w1, agg_b1, agg_w2, agg_b2, enc_w1, enc_b1, enc_w2, enc_b2, out);
}